// Round 4
// baseline (65.981 us; speedup 1.0000x reference)
//
#include <hip/hip_runtime.h>

// TemporalNorm: causal rolling-window (W=128) mean/var norm over time, per (b,d).
// x: [B,T,D] f32, weight/bias: [D] f32, out: [B,T,D] f32.
constexpr int Bb  = 32;
constexpr int Tt  = 4096;
constexpr int Dd  = 256;
constexpr int Ww  = 128;
constexpr float EPSF = 1e-5f;

constexpr int CT  = 128;           // time chunk (W/CT=1 -> fetch stays 1.0x)
constexpr int NC  = Tt / CT;       // 32 chunks
constexpr int TPC = Dd / 2;        // 128 threads per chunk (float2/thread)
constexpr int CPB = 2;             // 2 chunks per 256-thread block
constexpr int NWG = Bb * NC / CPB; // 512 blocks
constexpr int UF  = 8;             // time unroll / pipeline group

__global__ __launch_bounds__(256, 2)
void TemporalNorm_kernel(const float* __restrict__ x,
                         const float* __restrict__ wgt,
                         const float* __restrict__ bia,
                         float* __restrict__ out) {
    // XCD-contiguous swizzle (NWG % 8 == 0 -> bijective).
    const int i  = blockIdx.x;
    const int lb = (i & 7) * (NWG / 8) + (i >> 3);
    const int b     = lb / (NC / CPB);
    const int cpair = lb % (NC / CPB);
    const int sub   = threadIdx.x / TPC;
    const int d2    = threadIdx.x % TPC;
    const int c  = cpair * CPB + sub;
    const int t0 = c * CT;

    const float2* __restrict__ xb = reinterpret_cast<const float2*>(x   + (size_t)b * Tt * Dd) + d2;
    float2*       __restrict__ ob = reinterpret_cast<float2*>      (out + (size_t)b * Tt * Dd) + d2;
    const float wx = wgt[2 * d2], wy = wgt[2 * d2 + 1];
    const float bx = bia[2 * d2], by = bia[2 * d2 + 1];
    constexpr int S = Dd / 2;

    float s1x = 0.f, s2x = 0.f, s1y = 0.f, s2y = 0.f;

    if (t0 >= Ww) {
        // ---- steady state: window always full (n = W) ----
        // warm-up over [t0-W, t0): unroll x8, dual accumulators
        {
            float u1x = 0.f, u2x = 0.f, u1y = 0.f, u2y = 0.f;
            for (int t = t0 - Ww; t < t0; t += UF) {
                float2 a[UF];
#pragma unroll
                for (int j = 0; j < UF; ++j) a[j] = xb[(t + j) * S];
#pragma unroll
                for (int j = 0; j < UF; j += 2) {
                    s1x += a[j].x;  s2x += a[j].x * a[j].x;
                    s1y += a[j].y;  s2y += a[j].y * a[j].y;
                    u1x += a[j+1].x; u2x += a[j+1].x * a[j+1].x;
                    u1y += a[j+1].y; u2y += a[j+1].y * a[j+1].y;
                }
            }
            s1x += u1x; s2x += u2x; s1y += u1y; s2y += u2y;
        }

        const float rn = 1.0f / (float)Ww;   // exact (1/128)
        auto step = [&](float a, float o, float& s1, float& s2, float w, float bi) -> float {
            s1 += a - o;
            s2 += a * a - o * o;
            float loc = s1 * rn;
            float var = s2 * rn - loc * loc;
            return (a - loc) * rsqrtf(var + EPSF) * w + bi;
        };

        // software-pipelined main loop: prefetch group t+UF while computing group t.
        float2 A[UF], O[UF];
#pragma unroll
        for (int j = 0; j < UF; ++j) {
            A[j] = xb[(t0 + j) * S];
            O[j] = xb[(t0 + j - Ww) * S];
        }
        int tt = t0;
        for (; tt + UF < t0 + CT; tt += UF) {
            float2 An[UF], On[UF];
#pragma unroll
            for (int j = 0; j < UF; ++j) {
                An[j] = xb[(tt + UF + j) * S];
                On[j] = xb[(tt + UF + j - Ww) * S];
            }
#pragma unroll
            for (int j = 0; j < UF; ++j) {
                float2 r;
                r.x = step(A[j].x, O[j].x, s1x, s2x, wx, bx);
                r.y = step(A[j].y, O[j].y, s1y, s2y, wy, by);
                ob[(tt + j) * S] = r;
            }
#pragma unroll
            for (int j = 0; j < UF; ++j) { A[j] = An[j]; O[j] = On[j]; }
        }
        // epilogue group
#pragma unroll
        for (int j = 0; j < UF; ++j) {
            float2 r;
            r.x = step(A[j].x, O[j].x, s1x, s2x, wx, bx);
            r.y = step(A[j].y, O[j].y, s1y, s2y, wy, by);
            ob[(tt + j) * S] = r;
        }
    } else {
        // ---- chunk 0 (t0 == 0): growing window, n = t+1 (t < W) ----
        // group loads x4 so the serial scan isn't load-latency-bound
        for (int t = 0; t < CT; t += 4) {
            float2 a[4];
#pragma unroll
            for (int j = 0; j < 4; ++j) a[j] = xb[(t + j) * S];
#pragma unroll
            for (int j = 0; j < 4; ++j) {
                s1x += a[j].x; s2x += a[j].x * a[j].x;
                s1y += a[j].y; s2y += a[j].y * a[j].y;
                float rnv = 1.0f / (float)(t + j + 1);
                float lx = s1x * rnv, ly = s1y * rnv;
                float vx = s2x * rnv - lx * lx;
                float vy = s2y * rnv - ly * ly;
                float2 r;
                r.x = (a[j].x - lx) * rsqrtf(vx + EPSF) * wx + bx;
                r.y = (a[j].y - ly) * rsqrtf(vy + EPSF) * wy + by;
                ob[(t + j) * S] = r;
            }
        }
    }
}

extern "C" void kernel_launch(void* const* d_in, const int* in_sizes, int n_in,
                              void* d_out, int out_size, void* d_ws, size_t ws_size,
                              hipStream_t stream) {
    const float* x   = (const float*)d_in[0];
    const float* wgt = (const float*)d_in[1];
    const float* bia = (const float*)d_in[2];
    float* out = (float*)d_out;

    hipLaunchKernelGGL(TemporalNorm_kernel, dim3(NWG), dim3(256), 0, stream,
                       x, wgt, bia, out);
}

// Round 5
// 60.598 us; speedup vs baseline: 1.0888x; 1.0888x over previous
//
#include <hip/hip_runtime.h>

// TemporalNorm: causal rolling-window (W=128) mean/var norm over time, per (b,d).
// x: [B,T,D] f32, weight/bias: [D] f32, out: [B,T,D] f32.
constexpr int Bb  = 32;
constexpr int Tt  = 4096;
constexpr int Dd  = 256;
constexpr int Ww  = 128;
constexpr float EPSF = 1e-5f;

constexpr int CT  = 128;          // time chunk (W/CT=1 -> fetch stays 1.0x)
constexpr int NC  = Tt / CT;      // 32 chunks
constexpr int NWG = Bb * NC;      // 1024 blocks, 64 threads each (1 wave/chunk)
constexpr int S4  = Dd / 4;       // float4 stride per time step (64)

__global__ __launch_bounds__(64)
void TemporalNorm_kernel(const float* __restrict__ x,
                         const float* __restrict__ wgt,
                         const float* __restrict__ bia,
                         float* __restrict__ out) {
    // XCD-contiguous swizzle (NWG % 8 == 0 -> bijective): each XCD owns a
    // contiguous run of (b, chunk) so old-stream re-reads hit its L2.
    const int i  = blockIdx.x;
    const int lb = (i & 7) * (NWG / 8) + (i >> 3);
    const int b  = lb / NC;
    const int c  = lb % NC;
    const int d4 = threadIdx.x;          // float4 channel group (0..63)
    const int t0 = c * CT;

    const float4* __restrict__ xb = reinterpret_cast<const float4*>(x   + (size_t)b * Tt * Dd) + d4;
    float4*       __restrict__ ob = reinterpret_cast<float4*>      (out + (size_t)b * Tt * Dd) + d4;
    const float4 w4 = reinterpret_cast<const float4*>(wgt)[d4];
    const float4 b4 = reinterpret_cast<const float4*>(bia)[d4];

    float s1x = 0.f, s2x = 0.f, s1y = 0.f, s2y = 0.f;
    float s1z = 0.f, s2z = 0.f, s1w = 0.f, s2w = 0.f;

    if (t0 >= Ww) {
        // ---- steady state: window always full (n = W) ----
        // warm-up over [t0-W, t0): unroll x4 (16B/lane loads)
        for (int t = t0 - Ww; t < t0; t += 4) {
            float4 a0 = xb[(t + 0) * S4];
            float4 a1 = xb[(t + 1) * S4];
            float4 a2 = xb[(t + 2) * S4];
            float4 a3 = xb[(t + 3) * S4];
            s1x += (a0.x + a1.x) + (a2.x + a3.x);
            s2x += (a0.x * a0.x + a1.x * a1.x) + (a2.x * a2.x + a3.x * a3.x);
            s1y += (a0.y + a1.y) + (a2.y + a3.y);
            s2y += (a0.y * a0.y + a1.y * a1.y) + (a2.y * a2.y + a3.y * a3.y);
            s1z += (a0.z + a1.z) + (a2.z + a3.z);
            s2z += (a0.z * a0.z + a1.z * a1.z) + (a2.z * a2.z + a3.z * a3.z);
            s1w += (a0.w + a1.w) + (a2.w + a3.w);
            s2w += (a0.w * a0.w + a1.w * a1.w) + (a2.w * a2.w + a3.w * a3.w);
        }

        const float rn = 1.0f / (float)Ww;   // exact (1/128)
        auto step = [&](float a, float o, float& s1, float& s2, float w, float bi) -> float {
            s1 += a - o;
            s2 += a * a - o * o;
            float loc = s1 * rn;
            float var = s2 * rn - loc * loc;
            return (a - loc) * rsqrtf(var + EPSF) * w + bi;
        };

        for (int t = t0; t < t0 + CT; t += 4) {
            // 8 independent 16B loads per group
            float4 a0 = xb[(t + 0) * S4];
            float4 a1 = xb[(t + 1) * S4];
            float4 a2 = xb[(t + 2) * S4];
            float4 a3 = xb[(t + 3) * S4];
            float4 o0 = xb[(t + 0 - Ww) * S4];
            float4 o1 = xb[(t + 1 - Ww) * S4];
            float4 o2 = xb[(t + 2 - Ww) * S4];
            float4 o3 = xb[(t + 3 - Ww) * S4];

            float4 r0, r1, r2, r3;
            r0.x = step(a0.x, o0.x, s1x, s2x, w4.x, b4.x);
            r0.y = step(a0.y, o0.y, s1y, s2y, w4.y, b4.y);
            r0.z = step(a0.z, o0.z, s1z, s2z, w4.z, b4.z);
            r0.w = step(a0.w, o0.w, s1w, s2w, w4.w, b4.w);
            r1.x = step(a1.x, o1.x, s1x, s2x, w4.x, b4.x);
            r1.y = step(a1.y, o1.y, s1y, s2y, w4.y, b4.y);
            r1.z = step(a1.z, o1.z, s1z, s2z, w4.z, b4.z);
            r1.w = step(a1.w, o1.w, s1w, s2w, w4.w, b4.w);
            r2.x = step(a2.x, o2.x, s1x, s2x, w4.x, b4.x);
            r2.y = step(a2.y, o2.y, s1y, s2y, w4.y, b4.y);
            r2.z = step(a2.z, o2.z, s1z, s2z, w4.z, b4.z);
            r2.w = step(a2.w, o2.w, s1w, s2w, w4.w, b4.w);
            r3.x = step(a3.x, o3.x, s1x, s2x, w4.x, b4.x);
            r3.y = step(a3.y, o3.y, s1y, s2y, w4.y, b4.y);
            r3.z = step(a3.z, o3.z, s1z, s2z, w4.z, b4.z);
            r3.w = step(a3.w, o3.w, s1w, s2w, w4.w, b4.w);

            ob[(t + 0) * S4] = r0;
            ob[(t + 1) * S4] = r1;
            ob[(t + 2) * S4] = r2;
            ob[(t + 3) * S4] = r3;
        }
    } else {
        // ---- chunk 0 (t0 == 0): growing window, n = t+1 (t < W) ----
        for (int t = 0; t < CT; t += 4) {
            float4 a[4];
#pragma unroll
            for (int j = 0; j < 4; ++j) a[j] = xb[(t + j) * S4];
#pragma unroll
            for (int j = 0; j < 4; ++j) {
                s1x += a[j].x; s2x += a[j].x * a[j].x;
                s1y += a[j].y; s2y += a[j].y * a[j].y;
                s1z += a[j].z; s2z += a[j].z * a[j].z;
                s1w += a[j].w; s2w += a[j].w * a[j].w;
                float rnv = 1.0f / (float)(t + j + 1);
                float lx = s1x * rnv, ly = s1y * rnv, lz = s1z * rnv, lw = s1w * rnv;
                float4 r;
                r.x = (a[j].x - lx) * rsqrtf(s2x * rnv - lx * lx + EPSF) * w4.x + b4.x;
                r.y = (a[j].y - ly) * rsqrtf(s2y * rnv - ly * ly + EPSF) * w4.y + b4.y;
                r.z = (a[j].z - lz) * rsqrtf(s2z * rnv - lz * lz + EPSF) * w4.z + b4.z;
                r.w = (a[j].w - lw) * rsqrtf(s2w * rnv - lw * lw + EPSF) * w4.w + b4.w;
                ob[(t + j) * S4] = r;
            }
        }
    }
}

extern "C" void kernel_launch(void* const* d_in, const int* in_sizes, int n_in,
                              void* d_out, int out_size, void* d_ws, size_t ws_size,
                              hipStream_t stream) {
    const float* x   = (const float*)d_in[0];
    const float* wgt = (const float*)d_in[1];
    const float* bia = (const float*)d_in[2];
    float* out = (float*)d_out;

    hipLaunchKernelGGL(TemporalNorm_kernel, dim3(NWG), dim3(64), 0, stream,
                       x, wgt, bia, out);
}